// Round 11
// baseline (191.004 us; speedup 1.0000x reference)
//
#include <hip/hip_runtime.h>

#define WIDTH 128
#define SLOPE 0.01f
#define SBS 512
#define FBM 16
#define ECAP 512

typedef __attribute__((ext_vector_type(8))) short short8;
typedef __attribute__((ext_vector_type(4))) float f32x4;

__device__ __forceinline__ unsigned short f2bf(float f) {
    unsigned b = __float_as_uint(f);
    b += 0x7FFFu + ((b >> 16) & 1u);   // round-to-nearest-even
    return (unsigned short)(b >> 16);
}
__device__ __forceinline__ float4 upk(uint2 u) {   // 4 bf16 -> 4 f32 (exact)
    float4 r;
    r.x = __uint_as_float(u.x << 16);
    r.y = __uint_as_float(u.x & 0xFFFF0000u);
    r.z = __uint_as_float(u.y << 16);
    r.w = __uint_as_float(u.y & 0xFFFF0000u);
    return r;
}
__device__ __forceinline__ float fbl(unsigned u) { return __uint_as_float(u << 16); }
__device__ __forceinline__ float fbh(unsigned u) { return __uint_as_float(u & 0xFFFF0000u); }
// elementwise tree-min of 4 bf16x8 vectors, accumulate into mn[8]
__device__ __forceinline__ void accum4(float mn[8], uint4 a, uint4 b, uint4 c, uint4 d) {
    mn[0] = fminf(mn[0], fminf(fminf(fbl(a.x), fbl(b.x)), fminf(fbl(c.x), fbl(d.x))));
    mn[1] = fminf(mn[1], fminf(fminf(fbh(a.x), fbh(b.x)), fminf(fbh(c.x), fbh(d.x))));
    mn[2] = fminf(mn[2], fminf(fminf(fbl(a.y), fbl(b.y)), fminf(fbl(c.y), fbl(d.y))));
    mn[3] = fminf(mn[3], fminf(fminf(fbh(a.y), fbh(b.y)), fminf(fbh(c.y), fbh(d.y))));
    mn[4] = fminf(mn[4], fminf(fminf(fbl(a.z), fbl(b.z)), fminf(fbl(c.z), fbl(d.z))));
    mn[5] = fminf(mn[5], fminf(fminf(fbh(a.z), fbh(b.z)), fminf(fbh(c.z), fbh(d.z))));
    mn[6] = fminf(mn[6], fminf(fminf(fbl(a.w), fbl(b.w)), fminf(fbl(c.w), fbl(d.w))));
    mn[7] = fminf(mn[7], fminf(fminf(fbh(a.w), fbh(b.w)), fminf(fbh(c.w), fbh(d.w))));
}
// XOR-swizzled LDS byte offset for row-major [16][512B] A tile (T2/G4)
__device__ __forceinline__ int swz(int lr, int bc) {
    return lr * 512 + (bc ^ ((lr & 7) << 4));
}

// ---------------- prep: xsb = bf16(x_src)  |  hist  |  W fold+transpose ----
__global__ void prep_kernel(const float* __restrict__ x_src,
                            const float* __restrict__ W,
                            const int* __restrict__ e,
                            unsigned short* __restrict__ xsb,
                            unsigned short* __restrict__ Wt,
                            unsigned* __restrict__ counts,
                            int NS, int E, int nconv, int nhist) {
    int b = blockIdx.x;
    if (b < nconv) {
        int i = b * 256 + threadIdx.x;          // float4 units over x_src
        if (i < NS * 32) {
            float4 v = reinterpret_cast<const float4*>(x_src)[i];
            ushort4 o;
            o.x = f2bf(v.x); o.y = f2bf(v.y); o.z = f2bf(v.z); o.w = f2bf(v.w);
            *reinterpret_cast<ushort4*>(xsb + (size_t)i * 4) = o;
        }
    } else if (b < nconv + nhist) {
        int i = (b - nconv) * 256 + threadIdx.x;
        if (i < E) atomicAdd(&counts[e[E + i]], 1u);
    } else {
        int t = (b - nconv - nhist) * 256 + threadIdx.x;
        if (t < 128 * 64) {
            int n = t & 127, kc = t >> 7;       // k = kc*4+j over 0..255
            ushort4 o;
            unsigned short* op = &o.x;
            #pragma unroll
            for (int j = 0; j < 4; ++j) {
                int k = kc * 4 + j;
                float v;
                if (k < 128) v = W[(size_t)k * 128 + n] + W[(size_t)(k + 128) * 128 + n];
                else         v = -W[(size_t)k * 128 + n];
                op[j] = f2bf(v);
            }
            *reinterpret_cast<ushort4*>(Wt + (size_t)n * 256 + kc * 4) = o;
        }
    }
}

// ---------------- scan + scatter (counting sort by dst) --------------------
__global__ void block_sum_kernel(const unsigned* __restrict__ counts,
                                 unsigned* __restrict__ bsums, int M) {
    int i = blockIdx.x * SBS + threadIdx.x;
    unsigned v = (i < M) ? counts[i] : 0u;
    for (int d = 32; d > 0; d >>= 1) v += __shfl_down(v, d);
    __shared__ unsigned ws[SBS / 64];
    int lane = threadIdx.x & 63, w = threadIdx.x >> 6;
    if (lane == 0) ws[w] = v;
    __syncthreads();
    if (threadIdx.x == 0) {
        unsigned s = 0;
        for (int k = 0; k < SBS / 64; ++k) s += ws[k];
        bsums[blockIdx.x] = s;
    }
}

__global__ void bsum_scan_kernel(const unsigned* __restrict__ bsums,
                                 unsigned* __restrict__ bbase, int NB,
                                 int* __restrict__ offsets, int M) {
    __shared__ unsigned s[256];
    int t = threadIdx.x;
    unsigned v = (t < NB) ? bsums[t] : 0u;
    s[t] = v;
    __syncthreads();
    for (int off = 1; off < 256; off <<= 1) {
        unsigned n = (t >= off) ? s[t - off] : 0u;
        __syncthreads();
        s[t] += n;
        __syncthreads();
    }
    if (t < NB) bbase[t] = s[t] - v;
    if (t == 255) offsets[M] = (int)s[255];
}

__global__ void scan_final_kernel(const unsigned* __restrict__ counts,
                                  const unsigned* __restrict__ bbase,
                                  int* __restrict__ offsets,
                                  int* __restrict__ cursor, int M) {
    int b = blockIdx.x, t = threadIdx.x;
    int i = b * SBS + t;
    unsigned c = (i < M) ? counts[i] : 0u;
    unsigned v = c;
    int lane = t & 63, w = t >> 6;
    for (int d = 1; d < 64; d <<= 1) {
        unsigned n = __shfl_up(v, d);
        if (lane >= d) v += n;
    }
    __shared__ unsigned ws[SBS / 64];
    if (lane == 63) ws[w] = v;
    __syncthreads();
    unsigned wbase = 0;
    for (int k = 0; k < w; ++k) wbase += ws[k];
    if (i < M) {
        int o = (int)(bbase[b] + wbase + v - c);
        offsets[i] = o;
        cursor[i] = o;
    }
}

__global__ void scatter_kernel(const int* __restrict__ e,
                               int* __restrict__ cursor,
                               int* __restrict__ csr, int E) {
    int i = blockIdx.x * blockDim.x + threadIdx.x;
    if (i < E) {
        int dst = e[E + i];
        int pos = atomicAdd(&cursor[dst], 1);
        csr[pos] = e[i];
    }
}

// ---------------- Fused: LDS-idx gather-min + MFMA GEMM --------------------
// Block = 16 rows, 4 waves. Each wave: 4 rows, 16 lanes/row (uint4 = 8 cols).
// Gather loop hand-unrolled x2: 8 independent uint4 loads in flight per lane
// (two accumulator sets break the register-reuse serialization seen at
// VGPR=36). Clamped duplicate edges are idempotent for min. M % FBM == 0.
template<int XSB>
__global__ __launch_bounds__(256, 6) void fused_kernel(
        const float* __restrict__ x_src,
        const unsigned short* __restrict__ xsb,
        const float* __restrict__ x_dst,
        const int* __restrict__ offsets,
        const int* __restrict__ csr,
        const unsigned short* __restrict__ Wt,
        const float* __restrict__ bias,
        float* __restrict__ out, int M) {
    __shared__ __align__(16) unsigned short At[FBM * 256];  // 8 KB
    __shared__ __align__(16) int eidx[ECAP];                // 2 KB
    __shared__ int offs[FBM + 1];
    char* Ab = reinterpret_cast<char*>(At);
    int tid = threadIdx.x;
    int lane = tid & 63;
    int wv = tid >> 6;
    int blockRow = blockIdx.x * FBM;

    // ---- stage: offsets slice, xb tile, csr slice (one barrier) ----
    int ebeg = offsets[blockRow];
    int eend = offsets[blockRow + FBM];
    int ecount = eend - ebeg;
    if (tid <= FBM) offs[tid] = offsets[blockRow + tid];
    #pragma unroll
    for (int i = 0; i < FBM * 32 / 256; ++i) {   // 2 float4 per thread
        int u = tid + 256 * i;
        int lr = u >> 5, c4 = u & 31;
        float4 v = reinterpret_cast<const float4*>(x_dst)[(size_t)(blockRow + lr) * 32 + c4];
        ushort4 o;
        o.x = f2bf(v.x); o.y = f2bf(v.y); o.z = f2bf(v.z); o.w = f2bf(v.w);
        *reinterpret_cast<ushort4*>(Ab + swz(lr, c4 * 8)) = o;
    }
    bool fit = (ecount <= ECAP);
    for (int i = tid; i < min(ecount, ECAP); i += 256) eidx[i] = csr[ebeg + i];
    __syncthreads();

    // ---- gather-min: lane = (row rg, col-block l15); 8 edges/row/batch ----
    int l15 = lane & 15;
    int rg = lane >> 4;
    int lr = wv * 4 + rg;
    int rb = offs[lr] - ebeg;
    int re = offs[lr + 1] - ebeg;
    int deg = re - rb;
    int lim = re - 1;                       // may be rb-1 when deg==0
    int oA = offs[wv * 4], oB = offs[wv * 4 + 1], oC = offs[wv * 4 + 2];
    int oD = offs[wv * 4 + 3], oE = offs[wv * 4 + 4];
    int mb = max(max(oB - oA, oC - oB), max(oD - oC, oE - oD));

    float mnA[8], mnB[8];
    #pragma unroll
    for (int j = 0; j < 8; ++j) { mnA[j] = INFINITY; mnB[j] = INFINITY; }

    if (XSB && fit) {
        const uint4* xs = reinterpret_cast<const uint4*>(xsb);
        int nb8 = ((mb + 7) >> 3) << 3;
        for (int e0 = 0; e0 < nb8; e0 += 8) {
            int p0 = max(min(rb + e0 + 0, lim), 0);
            int p1 = max(min(rb + e0 + 1, lim), 0);
            int p2 = max(min(rb + e0 + 2, lim), 0);
            int p3 = max(min(rb + e0 + 3, lim), 0);
            int p4 = max(min(rb + e0 + 4, lim), 0);
            int p5 = max(min(rb + e0 + 5, lim), 0);
            int p6 = max(min(rb + e0 + 6, lim), 0);
            int p7 = max(min(rb + e0 + 7, lim), 0);
            int i0 = eidx[p0]; int i1 = eidx[p1];
            int i2 = eidx[p2]; int i3 = eidx[p3];
            int i4 = eidx[p4]; int i5 = eidx[p5];
            int i6 = eidx[p6]; int i7 = eidx[p7];
            uint4 v0 = xs[(size_t)i0 * 16 + l15];
            uint4 v1 = xs[(size_t)i1 * 16 + l15];
            uint4 v2 = xs[(size_t)i2 * 16 + l15];
            uint4 v3 = xs[(size_t)i3 * 16 + l15];
            uint4 v4 = xs[(size_t)i4 * 16 + l15];
            uint4 v5 = xs[(size_t)i5 * 16 + l15];
            uint4 v6 = xs[(size_t)i6 * 16 + l15];
            uint4 v7 = xs[(size_t)i7 * 16 + l15];
            accum4(mnA, v0, v1, v2, v3);
            accum4(mnB, v4, v5, v6, v7);
        }
    } else {
        // fallback (never hit with current ws sizing): simple 2-edge loop
        int nb2 = ((mb + 1) >> 1) << 1;
        for (int e0 = 0; e0 < nb2; e0 += 2) {
            int p0 = max(min(rb + e0 + 0, lim), 0);
            int p1 = max(min(rb + e0 + 1, lim), 0);
            int i0 = fit ? eidx[p0] : csr[ebeg + p0];
            int i1 = fit ? eidx[p1] : csr[ebeg + p1];
            if (XSB) {
                const uint4* xs = reinterpret_cast<const uint4*>(xsb);
                uint4 v0 = xs[(size_t)i0 * 16 + l15];
                uint4 v1 = xs[(size_t)i1 * 16 + l15];
                accum4(mnA, v0, v0, v1, v1);
            } else {
                const float4* xf = reinterpret_cast<const float4*>(x_src);
                float4 a0 = xf[(size_t)i0 * 32 + l15 * 2];
                float4 b0 = xf[(size_t)i0 * 32 + l15 * 2 + 1];
                float4 a1 = xf[(size_t)i1 * 32 + l15 * 2];
                float4 b1 = xf[(size_t)i1 * 32 + l15 * 2 + 1];
                mnA[0] = fminf(mnA[0], fminf(a0.x, a1.x));
                mnA[1] = fminf(mnA[1], fminf(a0.y, a1.y));
                mnA[2] = fminf(mnA[2], fminf(a0.z, a1.z));
                mnA[3] = fminf(mnA[3], fminf(a0.w, a1.w));
                mnA[4] = fminf(mnA[4], fminf(b0.x, b1.x));
                mnA[5] = fminf(mnA[5], fminf(b0.y, b1.y));
                mnA[6] = fminf(mnA[6], fminf(b0.z, b1.z));
                mnA[7] = fminf(mnA[7], fminf(b0.w, b1.w));
            }
        }
    }
    #pragma unroll
    for (int j = 0; j < 8; ++j) mnA[j] = fminf(mnA[j], mnB[j]);

    // ---- write mn half of A (this lane owns row lr, cols l15*8..+7) ----
    {
        ushort4 oa, ob;
        if (deg > 0) {
            oa.x = f2bf(mnA[0]); oa.y = f2bf(mnA[1]);
            oa.z = f2bf(mnA[2]); oa.w = f2bf(mnA[3]);
            ob.x = f2bf(mnA[4]); ob.y = f2bf(mnA[5]);
            ob.z = f2bf(mnA[6]); ob.w = f2bf(mnA[7]);
        } else {   // empty row: mn := xb  =>  h = xb@W0 exactly
            oa = *reinterpret_cast<const ushort4*>(Ab + swz(lr, l15 * 16));
            ob = *reinterpret_cast<const ushort4*>(Ab + swz(lr, l15 * 16 + 8));
        }
        *reinterpret_cast<ushort4*>(Ab + swz(lr, 256 + l15 * 16)) = oa;
        *reinterpret_cast<ushort4*>(Ab + swz(lr, 256 + l15 * 16 + 8)) = ob;
    }
    __syncthreads();

    // ---- MFMA GEMM: A (16x256) from LDS, B (folded W') from L2 ----
    int q = lane >> 4;
    int ncol0 = wv * 32;
    f32x4 acc0 = (f32x4){0.f, 0.f, 0.f, 0.f};
    f32x4 acc1 = (f32x4){0.f, 0.f, 0.f, 0.f};
    size_t b0off = (size_t)(ncol0 + l15) * 256;
    size_t b1off = (size_t)(ncol0 + 16 + l15) * 256;

    #pragma unroll
    for (int s = 0; s < 8; ++s) {
        int koff = s * 32 + q * 8;               // bf16 elements
        short8 b0 = *reinterpret_cast<const short8*>(Wt + b0off + koff);
        short8 b1 = *reinterpret_cast<const short8*>(Wt + b1off + koff);
        short8 a = *reinterpret_cast<const short8*>(Ab + swz(l15, koff * 2));
        // swapped operands: C col(lane&15)=out row, C row(q*4+reg)=out col
        acc0 = __builtin_amdgcn_mfma_f32_16x16x32_bf16(b0, a, acc0, 0, 0, 0);
        acc1 = __builtin_amdgcn_mfma_f32_16x16x32_bf16(b1, a, acc1, 0, 0, 0);
    }

    float4 bi0 = *reinterpret_cast<const float4*>(bias + ncol0 + q * 4);
    float4 bi1 = *reinterpret_cast<const float4*>(bias + ncol0 + 16 + q * 4);
    int row = blockRow + l15;                    // M % 16 == 0: always valid
    #pragma unroll
    for (int u = 0; u < 2; ++u) {
        int col = ncol0 + u * 16 + q * 4;
        f32x4 av = u ? acc1 : acc0;
        float4 bv = u ? bi1 : bi0;
        uint2 xu = *reinterpret_cast<const uint2*>(Ab + swz(l15, col * 2));
        float4 xb = upk(xu);
        float4 o;
        float h;
        h = av[0] + bv.x; o.x = xb.x + (h > 0.f ? h : SLOPE * h);
        h = av[1] + bv.y; o.y = xb.y + (h > 0.f ? h : SLOPE * h);
        h = av[2] + bv.z; o.z = xb.z + (h > 0.f ? h : SLOPE * h);
        h = av[3] + bv.w; o.w = xb.w + (h > 0.f ? h : SLOPE * h);
        *reinterpret_cast<float4*>(out + (size_t)row * 128 + col) = o;
    }
}

extern "C" void kernel_launch(void* const* d_in, const int* in_sizes, int n_in,
                              void* d_out, int out_size, void* d_ws, size_t ws_size,
                              hipStream_t stream) {
    const float* x_src = (const float*)d_in[0];
    const float* x_dst = (const float*)d_in[1];
    const int*   e     = (const int*)d_in[2];
    const float* W     = (const float*)d_in[3];
    const float* bias  = (const float*)d_in[4];
    float* out = (float*)d_out;

    int NS = in_sizes[0] / WIDTH;   // 100000 src nodes
    int E  = in_sizes[2] / 2;       // 800000
    int M  = in_sizes[1] / WIDTH;   // 100000 dst nodes
    int NB = (M + SBS - 1) / SBS;   // 196 (<= 256)

    // ws: xsb bf16[NS*128] | Wt bf16[128*256] | counts[M] | offsets[M+1] |
    //     cursor[M] | csr[E] | bsums[NB] | bbase[NB]    (~30 MB)
    unsigned short* xsb = (unsigned short*)d_ws;
    unsigned short* Wt  = xsb + (size_t)NS * WIDTH;
    unsigned* counts  = (unsigned*)(Wt + 128 * 256);
    int*      offsets = (int*)(counts + M);
    int*      cursor  = offsets + (M + 1);
    int*      csr     = cursor + M;
    unsigned* bsums   = (unsigned*)(csr + E);
    unsigned* bbase   = bsums + NB;
    size_t need = (char*)(bbase + NB) - (char*)d_ws;
    int use_xsb = (ws_size >= need) ? 1 : 0;
    if (!use_xsb) {   // fallback: no xsb; shift layout to skip it
        Wt = (unsigned short*)d_ws;
        counts  = (unsigned*)(Wt + 128 * 256);
        offsets = (int*)(counts + M);
        cursor  = offsets + (M + 1);
        csr     = cursor + M;
        bsums   = (unsigned*)(csr + E);
        bbase   = bsums + NB;
    }

    hipMemsetAsync(counts, 0, (size_t)M * sizeof(unsigned), stream);

    int nconv = use_xsb ? (NS * 32 + 255) / 256 : 0;
    int nhist = (E + 255) / 256;
    int nwt   = (128 * 64 + 255) / 256;
    prep_kernel<<<nconv + nhist + nwt, 256, 0, stream>>>(x_src, W, e, xsb, Wt,
                                                         counts, NS, E,
                                                         nconv, nhist);
    block_sum_kernel<<<NB, SBS, 0, stream>>>(counts, bsums, M);
    bsum_scan_kernel<<<1, 256, 0, stream>>>(bsums, bbase, NB, offsets, M);
    scan_final_kernel<<<NB, SBS, 0, stream>>>(counts, bbase, offsets, cursor, M);
    scatter_kernel<<<(E + 255) / 256, 256, 0, stream>>>(e, cursor, csr, E);

    int fblocks = (M + FBM - 1) / FBM;   // 6250
    if (use_xsb)
        fused_kernel<1><<<fblocks, 256, 0, stream>>>(x_src, xsb, x_dst, offsets,
                                                     csr, Wt, bias, out, M);
    else
        fused_kernel<0><<<fblocks, 256, 0, stream>>>(x_src, xsb, x_dst, offsets,
                                                     csr, Wt, bias, out, M);
}

// Round 12
// 146.903 us; speedup vs baseline: 1.3002x; 1.3002x over previous
//
#include <hip/hip_runtime.h>

#define WIDTH 128
#define SLOPE 0.01f
#define SBS 512
#define FBM 16
#define ECAP 512

typedef __attribute__((ext_vector_type(8))) short short8;
typedef __attribute__((ext_vector_type(4))) float f32x4;

__device__ __forceinline__ unsigned short f2bf(float f) {
    unsigned b = __float_as_uint(f);
    b += 0x7FFFu + ((b >> 16) & 1u);   // round-to-nearest-even
    return (unsigned short)(b >> 16);
}
__device__ __forceinline__ float4 upk(uint2 u) {   // 4 bf16 -> 4 f32 (exact)
    float4 r;
    r.x = __uint_as_float(u.x << 16);
    r.y = __uint_as_float(u.x & 0xFFFF0000u);
    r.z = __uint_as_float(u.y << 16);
    r.w = __uint_as_float(u.y & 0xFFFF0000u);
    return r;
}
// monotone bf16(u16) <-> u16 map: unsigned compare == float compare
__device__ __forceinline__ unsigned short map16(unsigned short x) {
    return (x & 0x8000u) ? (unsigned short)(~x) : (unsigned short)(x | 0x8000u);
}
__device__ __forceinline__ unsigned short unmap16(unsigned u) {
    return (unsigned short)((u & 0x8000u) ? (u ^ 0x8000u) : (~u & 0xFFFFu));
}
// packed unsigned-16 min (2 mapped bf16 per op), VOP3P
__device__ __forceinline__ unsigned pkmin(unsigned a, unsigned b) {
    unsigned r;
    asm("v_pk_min_u16 %0, %1, %2" : "=v"(r) : "v"(a), "v"(b));
    return r;
}
__device__ __forceinline__ uint4 pk4(uint4 a, uint4 b) {
    uint4 r;
    r.x = pkmin(a.x, b.x);
    r.y = pkmin(a.y, b.y);
    r.z = pkmin(a.z, b.z);
    r.w = pkmin(a.w, b.w);
    return r;
}
// XOR-swizzled LDS byte offset for row-major [16][512B] A tile (T2/G4)
__device__ __forceinline__ int swz(int lr, int bc) {
    return lr * 512 + (bc ^ ((lr & 7) << 4));
}

// ------- prep: xsb = map16(bf16(x_src)) | hist+rank | W fold+transpose -----
__global__ void prep_kernel(const float* __restrict__ x_src,
                            const float* __restrict__ W,
                            const int* __restrict__ e,
                            unsigned short* __restrict__ xsb,
                            unsigned short* __restrict__ Wt,
                            unsigned* __restrict__ counts,
                            int* __restrict__ rank,
                            int NS, int E, int nconv, int nhist) {
    int b = blockIdx.x;
    if (b < nconv) {
        int i = b * 256 + threadIdx.x;          // float4 units over x_src
        if (i < NS * 32) {
            float4 v = reinterpret_cast<const float4*>(x_src)[i];
            ushort4 o;
            o.x = map16(f2bf(v.x)); o.y = map16(f2bf(v.y));
            o.z = map16(f2bf(v.z)); o.w = map16(f2bf(v.w));
            *reinterpret_cast<ushort4*>(xsb + (size_t)i * 4) = o;
        }
    } else if (b < nconv + nhist) {
        int i = (b - nconv) * 256 + threadIdx.x;
        if (i < E) {
            int dst = e[E + i];
            rank[i] = (int)atomicAdd(&counts[dst], 1u);
        }
    } else {
        int t = (b - nconv - nhist) * 256 + threadIdx.x;
        if (t < 128 * 64) {
            int n = t & 127, kc = t >> 7;       // k = kc*4+j over 0..255
            ushort4 o;
            unsigned short* op = &o.x;
            #pragma unroll
            for (int j = 0; j < 4; ++j) {
                int k = kc * 4 + j;
                float v;
                if (k < 128) v = W[(size_t)k * 128 + n] + W[(size_t)(k + 128) * 128 + n];
                else         v = -W[(size_t)k * 128 + n];
                op[j] = f2bf(v);
            }
            *reinterpret_cast<ushort4*>(Wt + (size_t)n * 256 + kc * 4) = o;
        }
    }
}

// ---------------- scan + scatter (counting sort by dst) --------------------
__global__ void block_sum_kernel(const unsigned* __restrict__ counts,
                                 unsigned* __restrict__ bsums, int M) {
    int i = blockIdx.x * SBS + threadIdx.x;
    unsigned v = (i < M) ? counts[i] : 0u;
    for (int d = 32; d > 0; d >>= 1) v += __shfl_down(v, d);
    __shared__ unsigned ws[SBS / 64];
    int lane = threadIdx.x & 63, w = threadIdx.x >> 6;
    if (lane == 0) ws[w] = v;
    __syncthreads();
    if (threadIdx.x == 0) {
        unsigned s = 0;
        for (int k = 0; k < SBS / 64; ++k) s += ws[k];
        bsums[blockIdx.x] = s;
    }
}

__global__ void bsum_scan_kernel(const unsigned* __restrict__ bsums,
                                 unsigned* __restrict__ bbase, int NB,
                                 int* __restrict__ offsets, int M) {
    __shared__ unsigned s[256];
    int t = threadIdx.x;
    unsigned v = (t < NB) ? bsums[t] : 0u;
    s[t] = v;
    __syncthreads();
    for (int off = 1; off < 256; off <<= 1) {
        unsigned n = (t >= off) ? s[t - off] : 0u;
        __syncthreads();
        s[t] += n;
        __syncthreads();
    }
    if (t < NB) bbase[t] = s[t] - v;
    if (t == 255) offsets[M] = (int)s[255];
}

__global__ void scan_final_kernel(const unsigned* __restrict__ counts,
                                  const unsigned* __restrict__ bbase,
                                  int* __restrict__ offsets, int M) {
    int b = blockIdx.x, t = threadIdx.x;
    int i = b * SBS + t;
    unsigned c = (i < M) ? counts[i] : 0u;
    unsigned v = c;
    int lane = t & 63, w = t >> 6;
    for (int d = 1; d < 64; d <<= 1) {
        unsigned n = __shfl_up(v, d);
        if (lane >= d) v += n;
    }
    __shared__ unsigned ws[SBS / 64];
    if (lane == 63) ws[w] = v;
    __syncthreads();
    unsigned wbase = 0;
    for (int k = 0; k < w; ++k) wbase += ws[k];
    if (i < M) offsets[i] = (int)(bbase[b] + wbase + v - c);
}

__global__ void scatter_kernel(const int* __restrict__ e,
                               const int* __restrict__ offsets,
                               const int* __restrict__ rank,
                               int* __restrict__ csr, int E) {
    int i = blockIdx.x * blockDim.x + threadIdx.x;
    if (i < E) {
        int dst = e[E + i];
        csr[offsets[dst] + rank[i]] = e[i];
    }
}

// ---------------- Fused: LDS-idx gather-min + MFMA GEMM --------------------
// Block = 16 rows, 4 waves; each wave 4 rows x 16 lanes (uint4 = 8 cols).
// Straight-line 16-edge peel (P(deg>16)=.004): 16 independent gathers in
// flight per lane, reduced by a v_pk_min_u16 tree in the mapped-u16 domain.
// Clamped duplicate edges are idempotent for min. M % FBM == 0.
template<int XSB>
__global__ __launch_bounds__(256, 4) void fused_kernel(
        const float* __restrict__ x_src,
        const unsigned short* __restrict__ xsb,
        const float* __restrict__ x_dst,
        const int* __restrict__ offsets,
        const int* __restrict__ csr,
        const unsigned short* __restrict__ Wt,
        const float* __restrict__ bias,
        float* __restrict__ out, int M) {
    __shared__ __align__(16) unsigned short At[FBM * 256];  // 8 KB
    __shared__ __align__(16) int eidx[ECAP];                // 2 KB
    __shared__ int offs[FBM + 1];
    char* Ab = reinterpret_cast<char*>(At);
    int tid = threadIdx.x;
    int lane = tid & 63;
    int wv = tid >> 6;
    int blockRow = blockIdx.x * FBM;

    // ---- stage: offsets slice, xb tile, csr slice (one barrier) ----
    int ebeg = offsets[blockRow];
    int eend = offsets[blockRow + FBM];
    int ecount = eend - ebeg;
    if (tid <= FBM) offs[tid] = offsets[blockRow + tid];
    #pragma unroll
    for (int i = 0; i < FBM * 32 / 256; ++i) {   // 2 float4 per thread
        int u = tid + 256 * i;
        int lr = u >> 5, c4 = u & 31;
        float4 v = reinterpret_cast<const float4*>(x_dst)[(size_t)(blockRow + lr) * 32 + c4];
        ushort4 o;
        o.x = f2bf(v.x); o.y = f2bf(v.y); o.z = f2bf(v.z); o.w = f2bf(v.w);
        *reinterpret_cast<ushort4*>(Ab + swz(lr, c4 * 8)) = o;
    }
    bool fit = (ecount <= ECAP);
    for (int i = tid; i < min(ecount, ECAP); i += 256) eidx[i] = csr[ebeg + i];
    __syncthreads();

    // ---- gather-min: lane = (row rg, col-block l15) ----
    int l15 = lane & 15;
    int rg = lane >> 4;
    int lr = wv * 4 + rg;
    int rb = offs[lr] - ebeg;
    int re = offs[lr + 1] - ebeg;
    int deg = re - rb;
    int lim = re - 1;                       // rb-1 when deg==0
    int oA = offs[wv * 4], oB = offs[wv * 4 + 1], oC = offs[wv * 4 + 2];
    int oD = offs[wv * 4 + 3], oE = offs[wv * 4 + 4];
    int mb = max(max(oB - oA, oC - oB), max(oD - oC, oE - oD));  // wave-uniform

    uint4 mnv = make_uint4(~0u, ~0u, ~0u, ~0u);   // mapped-domain +inf

    if (XSB) {
        if (mb > 0) {   // wave-uniform guard: eidx[0] valid below
            const uint4* xs = reinterpret_cast<const uint4*>(xsb);
            int ix[16];
            #pragma unroll
            for (int j = 0; j < 16; ++j) {
                int p = max(min(rb + j, lim), 0);
                ix[j] = fit ? eidx[p] : csr[ebeg + p];
            }
            uint4 v[16];
            #pragma unroll
            for (int j = 0; j < 16; ++j) v[j] = xs[(size_t)ix[j] * 16 + l15];
            #pragma unroll
            for (int s = 8; s >= 1; s >>= 1)
                #pragma unroll
                for (int j = 0; j < s; ++j) v[j] = pk4(v[j], v[j + s]);
            mnv = v[0];
            // rare tail: deg > 16
            for (int e0 = 16; e0 < mb; e0 += 8) {
                uint4 t[8];
                #pragma unroll
                for (int j = 0; j < 8; ++j) {
                    int p = max(min(rb + e0 + j, lim), 0);
                    int iv = fit ? eidx[p] : csr[ebeg + p];
                    t[j] = xs[(size_t)iv * 16 + l15];
                }
                #pragma unroll
                for (int s = 4; s >= 1; s >>= 1)
                    #pragma unroll
                    for (int j = 0; j < s; ++j) t[j] = pk4(t[j], t[j + s]);
                mnv = pk4(mnv, t[0]);
            }
        }
    } else {
        // fallback (ws too small; never hit): f32 gather, map at the end
        float mn[8];
        #pragma unroll
        for (int j = 0; j < 8; ++j) mn[j] = INFINITY;
        const float4* xf = reinterpret_cast<const float4*>(x_src);
        for (int e0 = 0; e0 < mb; e0 += 2) {
            int p0 = max(min(rb + e0 + 0, lim), 0);
            int p1 = max(min(rb + e0 + 1, lim), 0);
            int i0 = fit ? eidx[p0] : csr[ebeg + p0];
            int i1 = fit ? eidx[p1] : csr[ebeg + p1];
            float4 a0 = xf[(size_t)i0 * 32 + l15 * 2];
            float4 b0 = xf[(size_t)i0 * 32 + l15 * 2 + 1];
            float4 a1 = xf[(size_t)i1 * 32 + l15 * 2];
            float4 b1 = xf[(size_t)i1 * 32 + l15 * 2 + 1];
            mn[0] = fminf(mn[0], fminf(a0.x, a1.x));
            mn[1] = fminf(mn[1], fminf(a0.y, a1.y));
            mn[2] = fminf(mn[2], fminf(a0.z, a1.z));
            mn[3] = fminf(mn[3], fminf(a0.w, a1.w));
            mn[4] = fminf(mn[4], fminf(b0.x, b1.x));
            mn[5] = fminf(mn[5], fminf(b0.y, b1.y));
            mn[6] = fminf(mn[6], fminf(b0.z, b1.z));
            mn[7] = fminf(mn[7], fminf(b0.w, b1.w));
        }
        mnv.x = (unsigned)map16(f2bf(mn[0])) | ((unsigned)map16(f2bf(mn[1])) << 16);
        mnv.y = (unsigned)map16(f2bf(mn[2])) | ((unsigned)map16(f2bf(mn[3])) << 16);
        mnv.z = (unsigned)map16(f2bf(mn[4])) | ((unsigned)map16(f2bf(mn[5])) << 16);
        mnv.w = (unsigned)map16(f2bf(mn[6])) | ((unsigned)map16(f2bf(mn[7])) << 16);
    }

    // ---- write mn half of A (this lane owns row lr, cols l15*8..+7) ----
    {
        ushort4 oa, ob;
        if (deg > 0) {
            oa.x = unmap16(mnv.x & 0xFFFFu); oa.y = unmap16(mnv.x >> 16);
            oa.z = unmap16(mnv.y & 0xFFFFu); oa.w = unmap16(mnv.y >> 16);
            ob.x = unmap16(mnv.z & 0xFFFFu); ob.y = unmap16(mnv.z >> 16);
            ob.z = unmap16(mnv.w & 0xFFFFu); ob.w = unmap16(mnv.w >> 16);
        } else {   // empty row: mn := xb  =>  h = xb@W0 exactly
            oa = *reinterpret_cast<const ushort4*>(Ab + swz(lr, l15 * 16));
            ob = *reinterpret_cast<const ushort4*>(Ab + swz(lr, l15 * 16 + 8));
        }
        *reinterpret_cast<ushort4*>(Ab + swz(lr, 256 + l15 * 16)) = oa;
        *reinterpret_cast<ushort4*>(Ab + swz(lr, 256 + l15 * 16 + 8)) = ob;
    }
    __syncthreads();

    // ---- MFMA GEMM: A (16x256) from LDS, B (folded W') from L2 ----
    int q = lane >> 4;
    int ncol0 = wv * 32;
    f32x4 acc0 = (f32x4){0.f, 0.f, 0.f, 0.f};
    f32x4 acc1 = (f32x4){0.f, 0.f, 0.f, 0.f};
    size_t b0off = (size_t)(ncol0 + l15) * 256;
    size_t b1off = (size_t)(ncol0 + 16 + l15) * 256;

    #pragma unroll
    for (int s = 0; s < 8; ++s) {
        int koff = s * 32 + q * 8;               // bf16 elements
        short8 b0 = *reinterpret_cast<const short8*>(Wt + b0off + koff);
        short8 b1 = *reinterpret_cast<const short8*>(Wt + b1off + koff);
        short8 a = *reinterpret_cast<const short8*>(Ab + swz(l15, koff * 2));
        // swapped operands: C col(lane&15)=out row, C row(q*4+reg)=out col
        acc0 = __builtin_amdgcn_mfma_f32_16x16x32_bf16(b0, a, acc0, 0, 0, 0);
        acc1 = __builtin_amdgcn_mfma_f32_16x16x32_bf16(b1, a, acc1, 0, 0, 0);
    }

    float4 bi0 = *reinterpret_cast<const float4*>(bias + ncol0 + q * 4);
    float4 bi1 = *reinterpret_cast<const float4*>(bias + ncol0 + 16 + q * 4);
    int row = blockRow + l15;                    // M % 16 == 0: always valid
    #pragma unroll
    for (int u = 0; u < 2; ++u) {
        int col = ncol0 + u * 16 + q * 4;
        f32x4 av = u ? acc1 : acc0;
        float4 bv = u ? bi1 : bi0;
        uint2 xu = *reinterpret_cast<const uint2*>(Ab + swz(l15, col * 2));
        float4 xb = upk(xu);
        float4 o;
        float h;
        h = av[0] + bv.x; o.x = xb.x + (h > 0.f ? h : SLOPE * h);
        h = av[1] + bv.y; o.y = xb.y + (h > 0.f ? h : SLOPE * h);
        h = av[2] + bv.z; o.z = xb.z + (h > 0.f ? h : SLOPE * h);
        h = av[3] + bv.w; o.w = xb.w + (h > 0.f ? h : SLOPE * h);
        *reinterpret_cast<float4*>(out + (size_t)row * 128 + col) = o;
    }
}

extern "C" void kernel_launch(void* const* d_in, const int* in_sizes, int n_in,
                              void* d_out, int out_size, void* d_ws, size_t ws_size,
                              hipStream_t stream) {
    const float* x_src = (const float*)d_in[0];
    const float* x_dst = (const float*)d_in[1];
    const int*   e     = (const int*)d_in[2];
    const float* W     = (const float*)d_in[3];
    const float* bias  = (const float*)d_in[4];
    float* out = (float*)d_out;

    int NS = in_sizes[0] / WIDTH;   // 100000 src nodes
    int E  = in_sizes[2] / 2;       // 800000
    int M  = in_sizes[1] / WIDTH;   // 100000 dst nodes
    int NB = (M + SBS - 1) / SBS;   // 196 (<= 256)

    // ws: xsb(mapped bf16)[NS*128] | Wt bf16[128*256] | counts[M] |
    //     offsets[M+1] | rank[E] | csr[E] | bsums[NB] | bbase[NB]   (~33 MB)
    unsigned short* xsb = (unsigned short*)d_ws;
    unsigned short* Wt  = xsb + (size_t)NS * WIDTH;
    unsigned* counts  = (unsigned*)(Wt + 128 * 256);
    int*      offsets = (int*)(counts + M);
    int*      rank    = offsets + (M + 1);
    int*      csr     = rank + E;
    unsigned* bsums   = (unsigned*)(csr + E);
    unsigned* bbase   = bsums + NB;
    size_t need = (char*)(bbase + NB) - (char*)d_ws;
    int use_xsb = (ws_size >= need) ? 1 : 0;
    if (!use_xsb) {   // fallback: no xsb; shift layout to skip it
        Wt = (unsigned short*)d_ws;
        counts  = (unsigned*)(Wt + 128 * 256);
        offsets = (int*)(counts + M);
        rank    = offsets + (M + 1);
        csr     = rank + E;
        bsums   = (unsigned*)(csr + E);
        bbase   = bsums + NB;
    }

    hipMemsetAsync(counts, 0, (size_t)M * sizeof(unsigned), stream);

    int nconv = use_xsb ? (NS * 32 + 255) / 256 : 0;
    int nhist = (E + 255) / 256;
    int nwt   = (128 * 64 + 255) / 256;
    prep_kernel<<<nconv + nhist + nwt, 256, 0, stream>>>(x_src, W, e, xsb, Wt,
                                                         counts, rank, NS, E,
                                                         nconv, nhist);
    block_sum_kernel<<<NB, SBS, 0, stream>>>(counts, bsums, M);
    bsum_scan_kernel<<<1, 256, 0, stream>>>(bsums, bbase, NB, offsets, M);
    scan_final_kernel<<<NB, SBS, 0, stream>>>(counts, bbase, offsets, M);
    scatter_kernel<<<(E + 255) / 256, 256, 0, stream>>>(e, offsets, rank, csr, E);

    int fblocks = (M + FBM - 1) / FBM;   // 6250
    if (use_xsb)
        fused_kernel<1><<<fblocks, 256, 0, stream>>>(x_src, xsb, x_dst, offsets,
                                                     csr, Wt, bias, out, M);
    else
        fused_kernel<0><<<fblocks, 256, 0, stream>>>(x_src, xsb, x_dst, offsets,
                                                     csr, Wt, bias, out, M);
}